// Round 6
// baseline (166.750 us; speedup 1.0000x reference)
//
#include <hip/hip_runtime.h>
#include <hip/hip_bf16.h>

// Problem constants (JointAnfisNet)
#define BATCH      16384
#define N_IN       6
#define N_MF       5
#define N_FUZZ     30      // N_IN * N_MF
#define N_RULES    2048
#define N_OUT_MEM  12

// Fused single-kernel decomposition (R6):
//   grid = 64 row-groups x 4 rule-splits = 256 blocks (1/CU).
//   block = 256 rows x 512 rules; lane covers 4 rows packed as f16x4 (uint2),
//   one ds_read_b64 serves 4 rows. Rule prep folded per-block into LDS;
//   finalize folded in via last-block-done (threadfence + device atomics).
//   Rationale: R5 evidence says dur_us = ~40us ws-poison + ~5-10us per
//   dispatch + kernel work; 3 dispatches -> 1 removes ~15-20us.
#define ROWS_PB    256
#define SPLITS     4
#define RULES_PB   (N_RULES / SPLITS)     // 512
#define THREADS    1024
#define WAVES      16
#define RULES_PW   (RULES_PB / WAVES)     // 32
#define ROWGROUPS  (BATCH / ROWS_PB)      // 64

// d_ws layout: partials f32[SPLITS*3*BATCH] = 768 KB @ 0; counters int[64] after.
#define WS_PART_OFF  0
#define WS_CNT_OFF   (SPLITS * 3 * BATCH * 4)

// Packed f16 pair; __builtin_elementwise_min lowers to v_pk_min_f16.
typedef _Float16 f16x2 __attribute__((ext_vector_type(2)));

// ---------------------------------------------------------------------------
// Deterministic dtype probe: mf_scales is genuinely in [0.5, 1.5]. Interpret
// its first 60 bytes as 30 bf16 halves; all-in-[0.4,1.6] => bf16 data
// (P(false positive for f32 data) ~ 1e-32). R3/R5 passed with this probe.
// ---------------------------------------------------------------------------
__device__ inline int probe_is_bf16(const void* mfs) {
    const unsigned int* w = (const unsigned int*)mfs;
    int ok = 1;
    for (int k = 0; k < 15; ++k) {
        const unsigned int v = w[k];
        const float lo = __uint_as_float(v << 16);
        const float hi = __uint_as_float(v & 0xffff0000u);
        if (!(lo >= 0.4f && lo <= 1.6f && hi >= 0.4f && hi <= 1.6f)) { ok = 0; break; }
    }
    return ok;
}

__global__ __launch_bounds__(THREADS, 4)
void anfis_fused(const void* __restrict__ x_,
                 const void* __restrict__ mfc_,
                 const void* __restrict__ mfs_,
                 const void* __restrict__ oc_,
                 const int*  __restrict__ input_rules,
                 const int*  __restrict__ output_rules,
                 float* __restrict__ partials,
                 int*   __restrict__ counters,
                 void*  __restrict__ out_) {
    __shared__ float        xs[ROWS_PB * N_IN];     // 6 KB staged x
    __shared__ float2       cinv[N_FUZZ];           // (center, 1/scale)
    __shared__ uint2        fuzz4[N_FUZZ][64];      // 15 KB, 4 rows/lane f16x4
    __shared__ unsigned int packed_lds[RULES_PB];   // 2 KB (this split only)
    __shared__ float2       ow_lds[RULES_PB];       // 4 KB
    __shared__ float        pl1[WAVES][ROWS_PB];    // 16 KB
    __shared__ float        pd0[WAVES][ROWS_PB];    // 16 KB
    __shared__ float        pd1[WAVES][ROWS_PB];    // 16 KB
    __shared__ int          flag;
    __shared__ int          amLast;

    const int t     = threadIdx.x;
    const int g     = blockIdx.x >> 2;         // row group 0..63
    const int split = blockIdx.x & 3;          // rule split 0..3
    const int row0  = g * ROWS_PB;

    if (t == 0) flag = probe_is_bf16(mfs_);
    __syncthreads();
    const bool is_bf16 = (flag != 0);

    // ---- Stage B0: pack this split's 512 rules into LDS (broadcast-read
    // later by the wave-uniform rule loop). L2-resident: ~16 KB/block. ----
    for (int r2 = t; r2 < RULES_PB; r2 += THREADS) {
        const int r = split * RULES_PB + r2;
        const int* rp = input_rules + r * N_IN;
        unsigned int p = 0;
#pragma unroll
        for (int i = 0; i < N_IN; ++i) p |= ((unsigned int)rp[i] & 31u) << (5 * i);
        packed_lds[r2] = p;
        const int o0i = output_rules[2 * r + 0];
        const int o1i = output_rules[2 * r + 1];
        float o0, o1;
        if (is_bf16) {
            const unsigned short* oc = (const unsigned short*)oc_;
            o0 = __uint_as_float((unsigned int)oc[o0i] << 16);
            o1 = __uint_as_float((unsigned int)oc[o1i] << 16);
        } else {
            const float* oc = (const float*)oc_;
            o0 = oc[o0i]; o1 = oc[o1i];
        }
        ow_lds[r2] = make_float2(o0, o1);
    }

    // ---- Stage B1: stage x rows + MF params into LDS ----
    if (is_bf16) {
        const unsigned short* xp = (const unsigned short*)x_ + row0 * N_IN;
        for (int i = t; i < ROWS_PB * N_IN; i += THREADS)
            xs[i] = __uint_as_float((unsigned int)xp[i] << 16);
    } else {
        const float* xp = (const float*)x_ + row0 * N_IN;
        for (int i = t; i < ROWS_PB * N_IN; i += THREADS) xs[i] = xp[i];
    }
    if (t < N_FUZZ) {
        float c, s;
        if (is_bf16) {
            c = __uint_as_float((unsigned int)((const unsigned short*)mfc_)[t] << 16);
            s = __uint_as_float((unsigned int)((const unsigned short*)mfs_)[t] << 16);
        } else {
            c = ((const float*)mfc_)[t];
            s = ((const float*)mfs_)[t];
        }
        cinv[t] = make_float2(c, 1.0f / s);
    }
    __syncthreads();

    // ---- Stage B2: fuzzify. 30 x 64 uint2, each = 4 rows' exp(-z^2) as f16 ----
    for (int e = t; e < N_FUZZ * 64; e += THREADS) {
        const int v    = e >> 6;    // MF value index 0..29
        const int lane = e & 63;
        const int i    = v / N_MF;  // input index
        const float2 ci = cinv[v];
        float f[4];
#pragma unroll
        for (int k = 0; k < 4; ++k) {
            const float z = (xs[(lane + 64 * k) * N_IN + i] - ci.x) * ci.y;
            f[k] = __expf(-z * z);
        }
        f16x2 a = { (_Float16)f[0], (_Float16)f[1] };   // rows lane, lane+64
        f16x2 b = { (_Float16)f[2], (_Float16)f[3] };   // rows lane+128, +192
        uint2 u;
        u.x = __builtin_bit_cast(unsigned int, a);
        u.y = __builtin_bit_cast(unsigned int, b);
        fuzz4[v][lane] = u;
    }
    __syncthreads();

    // ---- Stage C: rule loop. Wave-uniform r2 -> packed/ow are LDS
    // broadcast reads; the 6 fuzz gathers are conflict-free ds_read_b64. ----
    const int lane = t & 63;
    const int wave = __builtin_amdgcn_readfirstlane(t >> 6);
    const uint2* fz = &fuzz4[0][0];

    float l1[4] = {0.f, 0.f, 0.f, 0.f};
    float d0[4] = {0.f, 0.f, 0.f, 0.f};
    float d1[4] = {0.f, 0.f, 0.f, 0.f};

    const int rbase = wave * RULES_PW;
#pragma unroll 4
    for (int j = 0; j < RULES_PW; ++j) {
        const int r2 = rbase + j;
        const unsigned int p = packed_lds[r2];   // uniform -> LDS broadcast
        const float2 o = ow_lds[r2];             // uniform -> LDS broadcast
        const uint2 g0 = fz[((p      ) & 31u) * 64 + lane];
        const uint2 g1 = fz[((p >> 5 ) & 31u) * 64 + lane];
        const uint2 g2 = fz[((p >> 10) & 31u) * 64 + lane];
        const uint2 g3 = fz[((p >> 15) & 31u) * 64 + lane];
        const uint2 g4 = fz[((p >> 20) & 31u) * 64 + lane];
        const uint2 g5 = fz[((p >> 25) & 31u) * 64 + lane];
        f16x2 wa = __builtin_elementwise_min(__builtin_bit_cast(f16x2, g0.x),
                                             __builtin_bit_cast(f16x2, g1.x));
        wa = __builtin_elementwise_min(wa, __builtin_bit_cast(f16x2, g2.x));
        wa = __builtin_elementwise_min(wa, __builtin_bit_cast(f16x2, g3.x));
        wa = __builtin_elementwise_min(wa, __builtin_bit_cast(f16x2, g4.x));
        wa = __builtin_elementwise_min(wa, __builtin_bit_cast(f16x2, g5.x));
        f16x2 wb = __builtin_elementwise_min(__builtin_bit_cast(f16x2, g0.y),
                                             __builtin_bit_cast(f16x2, g1.y));
        wb = __builtin_elementwise_min(wb, __builtin_bit_cast(f16x2, g2.y));
        wb = __builtin_elementwise_min(wb, __builtin_bit_cast(f16x2, g3.y));
        wb = __builtin_elementwise_min(wb, __builtin_bit_cast(f16x2, g4.y));
        wb = __builtin_elementwise_min(wb, __builtin_bit_cast(f16x2, g5.y));
        const float w0 = (float)wa.x, w1 = (float)wa.y;
        const float w2 = (float)wb.x, w3 = (float)wb.y;
        l1[0] += w0; d0[0] += w0 * o.x; d1[0] += w0 * o.y;
        l1[1] += w1; d0[1] += w1 * o.x; d1[1] += w1 * o.y;
        l1[2] += w2; d0[2] += w2 * o.x; d1[2] += w2 * o.y;
        l1[3] += w3; d0[3] += w3 * o.x; d1[3] += w3 * o.y;
    }
#pragma unroll
    for (int k = 0; k < 4; ++k) {
        pl1[wave][lane + 64 * k] = l1[k];
        pd0[wave][lane + 64 * k] = d0[k];
        pd1[wave][lane + 64 * k] = d1[k];
    }
    __syncthreads();

    // ---- Stage D: reduce 16 wave-partials per row; write split partials ----
    if (t < ROWS_PB) {
        float a = 0.f, b = 0.f, c = 0.f;
#pragma unroll
        for (int wv = 0; wv < WAVES; ++wv) {
            a += pl1[wv][t];
            b += pd0[wv][t];
            c += pd1[wv][t];
        }
        const int row = row0 + t;
        partials[(split * 3 + 0) * BATCH + row] = a;
        partials[(split * 3 + 1) * BATCH + row] = b;
        partials[(split * 3 + 2) * BATCH + row] = c;
    }
    // Make partial writes visible device-wide before signaling (G16:
    // cross-XCD requires device-scope fence + atomics).
    __threadfence();
    if (t == 0) {
        const int old = atomicAdd(&counters[g], 1);
        amLast = (old == SPLITS - 1);
    }
    __syncthreads();

    // ---- Stage E: last block for this row-group finalizes its 256 rows ----
    if (amLast) {
        __threadfence();   // acquire: order partial reads after the atomic
        if (t < ROWS_PB) {
            const int row = row0 + t;
            float l1s = 0.f, d0s = 0.f, d1s = 0.f;
#pragma unroll
            for (int s = 0; s < SPLITS; ++s) {
                l1s += partials[(s * 3 + 0) * BATCH + row];
                d0s += partials[(s * 3 + 1) * BATCH + row];
                d1s += partials[(s * 3 + 2) * BATCH + row];
            }
            const float inv = 1.0f / fmaxf(l1s, 1e-12f);
            const float y0 = tanhf(d0s * inv) * 4.00f + 0.00f;
            const float y1 = tanhf(d1s * inv) * 0.75f + 0.75f;
            if (is_bf16) {
                __hip_bfloat162 o;
                o.x = __float2bfloat16(y0);
                o.y = __float2bfloat16(y1);
                ((__hip_bfloat162*)out_)[row] = o;
            } else {
                ((float2*)out_)[row] = make_float2(y0, y1);
            }
        }
    }
}

extern "C" void kernel_launch(void* const* d_in, const int* in_sizes, int n_in,
                              void* d_out, int out_size, void* d_ws, size_t ws_size,
                              hipStream_t stream) {
    (void)in_sizes; (void)n_in; (void)out_size; (void)ws_size;
    float* parts    = (float*)((char*)d_ws + WS_PART_OFF);
    int*   counters = (int*)((char*)d_ws + WS_CNT_OFF);

    // Counters must be zero every launch (d_ws is re-poisoned to 0xAA).
    // hipMemsetAsync is a graph-capturable node (the harness itself uses it).
    hipMemsetAsync(counters, 0, ROWGROUPS * sizeof(int), stream);

    anfis_fused<<<ROWGROUPS * SPLITS, THREADS, 0, stream>>>(
        d_in[0], d_in[1], d_in[2], d_in[3],
        (const int*)d_in[4], (const int*)d_in[5],
        parts, counters, d_out);
}

// Round 7
// 108.884 us; speedup vs baseline: 1.5314x; 1.5314x over previous
//
#include <hip/hip_runtime.h>
#include <hip/hip_bf16.h>

// Problem constants (JointAnfisNet)
#define BATCH      16384
#define N_IN       6
#define N_MF       5
#define N_FUZZ     30      // N_IN * N_MF
#define N_RULES    2048
#define N_OUT_MEM  12

// R7 decomposition (occupancy fix; R6 post-mortem):
//   grid = 64 row-groups x 8 rule-splits = 512 blocks -> 2 blocks/CU
//   (32 waves/CU = 8/SIMD, vs R5's 16/CU). LDS cut from ~70 KB to ~25 KB by
//   replacing the [16][256]x3 wave-partial arrays with a [3][256] accumulator
//   reduced via LDS float atomics (ds_add_f32). 3 dispatches again: R6 proved
//   launch gaps ~0 and the in-kernel device-fence finalize cost ~90 us.
#define ROWS_PB    256
#define SPLITS     8
#define RULES_PB   (N_RULES / SPLITS)     // 256
#define THREADS    1024
#define WAVES      16
#define RULES_PW   (RULES_PB / WAVES)     // 16
#define ROWGROUPS  (BATCH / ROWS_PB)      // 64

// d_ws layout (ws_size ~256 MB per R3/R5 WRITE_SIZE evidence; we use ~1.6 MB)
#define WS_PACKED_OFF  0                       // u32[2048]    = 8 KB
#define WS_OW_OFF      8192                    // float2[2048] = 16 KB
#define WS_PART_OFF    24576                   // f32[SPLITS*3*BATCH] = 1.5 MB

// Packed f16 pair; __builtin_elementwise_min lowers to v_pk_min_f16.
typedef _Float16 f16x2 __attribute__((ext_vector_type(2)));

// ---------------------------------------------------------------------------
// Deterministic dtype probe: mf_scales is genuinely in [0.5, 1.5]. Interpret
// its first 60 bytes as 30 bf16 halves; all-in-[0.4,1.6] => bf16 data
// (P(false positive for f32 data) ~ 1e-32). R3/R5/R6 passed with this probe.
// ---------------------------------------------------------------------------
__device__ inline int probe_is_bf16(const void* mfs) {
    const unsigned int* w = (const unsigned int*)mfs;
    int ok = 1;
    for (int k = 0; k < 15; ++k) {
        const unsigned int v = w[k];
        const float lo = __uint_as_float(v << 16);
        const float hi = __uint_as_float(v & 0xffff0000u);
        if (!(lo >= 0.4f && lo <= 1.6f && hi >= 0.4f && hi <= 1.6f)) { ok = 0; break; }
    }
    return ok;
}

// ---------------------------------------------------------------------------
// Prep: pack each rule's 6 MF indices (5 bits each) into u32, pre-gather
// out_centers[output_rules] -> float2. Written to d_ws so the main kernel's
// wave-uniform rule loop reads them via the SCALAR pipe (s_load), not LDS.
// ---------------------------------------------------------------------------
__global__ void anfis_prep(const int* __restrict__ input_rules,
                           const int* __restrict__ output_rules,
                           const void* __restrict__ oc_,
                           const void* __restrict__ mfs_,
                           unsigned int* __restrict__ packed,
                           float2* __restrict__ ow) {
    __shared__ int flag;
    if (threadIdx.x == 0) flag = probe_is_bf16(mfs_);
    __syncthreads();
    const bool is_bf16 = (flag != 0);

    const int r = blockIdx.x * blockDim.x + threadIdx.x;
    if (r >= N_RULES) return;
    const int* rp = input_rules + r * N_IN;
    unsigned int p = 0;
#pragma unroll
    for (int i = 0; i < N_IN; ++i) p |= ((unsigned int)rp[i] & 31u) << (5 * i);
    packed[r] = p;

    const int o0i = output_rules[2 * r + 0];
    const int o1i = output_rules[2 * r + 1];
    float o0, o1;
    if (is_bf16) {
        const unsigned short* oc = (const unsigned short*)oc_;
        o0 = __uint_as_float((unsigned int)oc[o0i] << 16);
        o1 = __uint_as_float((unsigned int)oc[o1i] << 16);
    } else {
        const float* oc = (const float*)oc_;
        o0 = oc[o0i]; o1 = oc[o1i];
    }
    ow[r] = make_float2(o0, o1);
}

// ---------------------------------------------------------------------------
// Main: block = (row group g: 256 rows) x (rule split s: 256 rules).
//   lane (0..63) covers rows {l, l+64, l+128, l+192} packed as f16x4 (uint2);
//   one conflict-free ds_read_b64 serves 4 rows. wave (0..15) handles 16
//   rules, wave-uniform -> packed/ow on the scalar pipe. Cross-wave row
//   reduction via LDS float atomics into acc[3][256] (~3 KB, replaces 48 KB).
// ---------------------------------------------------------------------------
__global__ __launch_bounds__(THREADS, 4)
void anfis_main(const void* __restrict__ x_,
                const void* __restrict__ mfc_,
                const void* __restrict__ mfs_,
                const unsigned int* __restrict__ packed,
                const float2* __restrict__ ow,
                float* __restrict__ partials) {
    __shared__ float  xs[ROWS_PB * N_IN];      // 6 KB staged x
    __shared__ float2 cinv[N_FUZZ];            // (center, 1/scale)
    __shared__ uint2  fuzz4[N_FUZZ][64];       // 15 KB, 4 rows/lane f16x4
    __shared__ float  acc[3][ROWS_PB];         // 3 KB: l1/d0/d1 per row
    __shared__ int    flag;

    const int t     = threadIdx.x;
    const int g     = blockIdx.x >> 3;         // row group 0..63
    const int split = blockIdx.x & 7;          // rule split 0..7
    const int row0  = g * ROWS_PB;

    if (t == 0) flag = probe_is_bf16(mfs_);
    // zero the atomic accumulator (768 floats)
    if (t < 3 * ROWS_PB) acc[0][t] = 0.0f;
    __syncthreads();
    const bool is_bf16 = (flag != 0);

    // ---- stage x rows + MF params into LDS ----
    if (is_bf16) {
        const unsigned short* xp = (const unsigned short*)x_ + row0 * N_IN;
        for (int i = t; i < ROWS_PB * N_IN; i += THREADS)
            xs[i] = __uint_as_float((unsigned int)xp[i] << 16);
    } else {
        const float* xp = (const float*)x_ + row0 * N_IN;
        for (int i = t; i < ROWS_PB * N_IN; i += THREADS) xs[i] = xp[i];
    }
    if (t < N_FUZZ) {
        float c, s;
        if (is_bf16) {
            c = __uint_as_float((unsigned int)((const unsigned short*)mfc_)[t] << 16);
            s = __uint_as_float((unsigned int)((const unsigned short*)mfs_)[t] << 16);
        } else {
            c = ((const float*)mfc_)[t];
            s = ((const float*)mfs_)[t];
        }
        cinv[t] = make_float2(c, 1.0f / s);
    }
    __syncthreads();

    // ---- fuzzify: 30 x 64 uint2, each = 4 rows' exp(-z^2) as f16 ----
    for (int e = t; e < N_FUZZ * 64; e += THREADS) {
        const int v    = e >> 6;    // MF value index 0..29
        const int lane = e & 63;
        const int i    = v / N_MF;  // input index
        const float2 ci = cinv[v];
        float f[4];
#pragma unroll
        for (int k = 0; k < 4; ++k) {
            const float z = (xs[(lane + 64 * k) * N_IN + i] - ci.x) * ci.y;
            f[k] = __expf(-z * z);
        }
        f16x2 a = { (_Float16)f[0], (_Float16)f[1] };   // rows lane, lane+64
        f16x2 b = { (_Float16)f[2], (_Float16)f[3] };   // rows lane+128, +192
        uint2 u;
        u.x = __builtin_bit_cast(unsigned int, a);
        u.y = __builtin_bit_cast(unsigned int, b);
        fuzz4[v][lane] = u;
    }
    __syncthreads();

    // ---- rule loop: wave-uniform r -> scalar packed/ow, 6 b64 gathers ----
    const int lane = t & 63;
    const int wave = __builtin_amdgcn_readfirstlane(t >> 6);
    const uint2* fz = &fuzz4[0][0];

    float l1[4] = {0.f, 0.f, 0.f, 0.f};
    float d0[4] = {0.f, 0.f, 0.f, 0.f};
    float d1[4] = {0.f, 0.f, 0.f, 0.f};

    const int rbase = split * RULES_PB + wave * RULES_PW;
#pragma unroll 4
    for (int j = 0; j < RULES_PW; ++j) {
        const int r = rbase + j;
        const unsigned int p = packed[r];   // uniform -> scalar load
        const float2 o = ow[r];             // uniform -> scalar load
        const uint2 g0 = fz[((p      ) & 31u) * 64 + lane];
        const uint2 g1 = fz[((p >> 5 ) & 31u) * 64 + lane];
        const uint2 g2 = fz[((p >> 10) & 31u) * 64 + lane];
        const uint2 g3 = fz[((p >> 15) & 31u) * 64 + lane];
        const uint2 g4 = fz[((p >> 20) & 31u) * 64 + lane];
        const uint2 g5 = fz[((p >> 25) & 31u) * 64 + lane];
        f16x2 wa = __builtin_elementwise_min(__builtin_bit_cast(f16x2, g0.x),
                                             __builtin_bit_cast(f16x2, g1.x));
        wa = __builtin_elementwise_min(wa, __builtin_bit_cast(f16x2, g2.x));
        wa = __builtin_elementwise_min(wa, __builtin_bit_cast(f16x2, g3.x));
        wa = __builtin_elementwise_min(wa, __builtin_bit_cast(f16x2, g4.x));
        wa = __builtin_elementwise_min(wa, __builtin_bit_cast(f16x2, g5.x));
        f16x2 wb = __builtin_elementwise_min(__builtin_bit_cast(f16x2, g0.y),
                                             __builtin_bit_cast(f16x2, g1.y));
        wb = __builtin_elementwise_min(wb, __builtin_bit_cast(f16x2, g2.y));
        wb = __builtin_elementwise_min(wb, __builtin_bit_cast(f16x2, g3.y));
        wb = __builtin_elementwise_min(wb, __builtin_bit_cast(f16x2, g4.y));
        wb = __builtin_elementwise_min(wb, __builtin_bit_cast(f16x2, g5.y));
        const float w0 = (float)wa.x, w1 = (float)wa.y;
        const float w2 = (float)wb.x, w3 = (float)wb.y;
        l1[0] += w0; d0[0] += w0 * o.x; d1[0] += w0 * o.y;
        l1[1] += w1; d0[1] += w1 * o.x; d1[1] += w1 * o.y;
        l1[2] += w2; d0[2] += w2 * o.x; d1[2] += w2 * o.y;
        l1[3] += w3; d0[3] += w3 * o.x; d1[3] += w3 * o.y;
    }

    // ---- cross-wave reduction: LDS float atomics (ds_add_f32). Bank =
    // row%32 -> free 2-way within a wave; 16-way cross-wave serialization
    // only on matching addresses, ~192 wave-ops total. ----
#pragma unroll
    for (int k = 0; k < 4; ++k) {
        const int row = lane + 64 * k;
        atomicAdd(&acc[0][row], l1[k]);
        atomicAdd(&acc[1][row], d0[k]);
        atomicAdd(&acc[2][row], d1[k]);
    }
    __syncthreads();

    // ---- write this split's partials ----
    if (t < ROWS_PB) {
        const int row = row0 + t;
        partials[(split * 3 + 0) * BATCH + row] = acc[0][t];
        partials[(split * 3 + 1) * BATCH + row] = acc[1][t];
        partials[(split * 3 + 2) * BATCH + row] = acc[2][t];
    }
}

// ---------------------------------------------------------------------------
// Finalize: sum the 8 rule-split partials per row, normalize, tanh, store.
// ---------------------------------------------------------------------------
__global__ void anfis_finalize(const float* __restrict__ partials,
                               const void* __restrict__ mfs_,
                               void* __restrict__ out_) {
    __shared__ int flag;
    if (threadIdx.x == 0) flag = probe_is_bf16(mfs_);
    __syncthreads();
    const int row = blockIdx.x * blockDim.x + threadIdx.x;
    if (row >= BATCH) return;
    float l1 = 0.f, d0 = 0.f, d1 = 0.f;
#pragma unroll
    for (int s = 0; s < SPLITS; ++s) {
        l1 += partials[(s * 3 + 0) * BATCH + row];
        d0 += partials[(s * 3 + 1) * BATCH + row];
        d1 += partials[(s * 3 + 2) * BATCH + row];
    }
    const float inv = 1.0f / fmaxf(l1, 1e-12f);
    const float y0 = tanhf(d0 * inv) * 4.00f + 0.00f;
    const float y1 = tanhf(d1 * inv) * 0.75f + 0.75f;
    if (flag) {
        __hip_bfloat162 o;
        o.x = __float2bfloat16(y0);
        o.y = __float2bfloat16(y1);
        ((__hip_bfloat162*)out_)[row] = o;
    } else {
        ((float2*)out_)[row] = make_float2(y0, y1);
    }
}

extern "C" void kernel_launch(void* const* d_in, const int* in_sizes, int n_in,
                              void* d_out, int out_size, void* d_ws, size_t ws_size,
                              hipStream_t stream) {
    (void)in_sizes; (void)n_in; (void)out_size; (void)ws_size;
    const void* x_   = d_in[0];
    const void* mfc_ = d_in[1];
    const void* mfs_ = d_in[2];
    const void* oc_  = d_in[3];
    const int* input_rules  = (const int*)d_in[4];
    const int* output_rules = (const int*)d_in[5];

    unsigned int* packed = (unsigned int*)((char*)d_ws + WS_PACKED_OFF);
    float2*       ow     = (float2*)((char*)d_ws + WS_OW_OFF);
    float*        parts  = (float*)((char*)d_ws + WS_PART_OFF);

    anfis_prep<<<(N_RULES + 255) / 256, 256, 0, stream>>>(
        input_rules, output_rules, oc_, mfs_, packed, ow);

    anfis_main<<<ROWGROUPS * SPLITS, THREADS, 0, stream>>>(
        x_, mfc_, mfs_, packed, ow, parts);

    anfis_finalize<<<BATCH / 256, 256, 0, stream>>>(parts, mfs_, d_out);
}

// Round 8
// 108.263 us; speedup vs baseline: 1.5402x; 1.0057x over previous
//
#include <hip/hip_runtime.h>
#include <hip/hip_bf16.h>

// Problem constants (JointAnfisNet)
#define BATCH      16384
#define N_IN       6
#define N_MF       5
#define N_FUZZ     30      // N_IN * N_MF
#define N_RULES    2048

// R8: R7 structure, but the rule loop is PURE LDS (rule data staged per-block
// into LDS; R7's per-rule s_loads shared lgkmcnt with ds_read and SMEM returns
// out-of-order -> every scalar wait was a full LDS-pipeline drain). Prep
// kernel folded in; probe made branchless/parallel; xs transposed.
#define ROWS_PB    256
#define SPLITS     8
#define RULES_PB   (N_RULES / SPLITS)     // 256
#define THREADS    1024
#define WAVES      16
#define RULES_PW   (RULES_PB / WAVES)     // 16
#define ROWGROUPS  (BATCH / ROWS_PB)      // 64

// d_ws layout: partials f32[SPLITS*3*BATCH] = 1.5 MB
#define WS_PART_OFF  0

// Packed f16 pair; __builtin_elementwise_min lowers to v_pk_min_f16.
typedef _Float16 f16x2 __attribute__((ext_vector_type(2)));

// ---------------------------------------------------------------------------
// Deterministic dtype probe (branchless: 15 INDEPENDENT loads -> one wait,
// vs R7's serial dependent chain with early-exit). mf_scales is genuinely in
// [0.5,1.5]; read as 30 bf16 halves, all-in-[0.4,1.6] => bf16 data
// (P(false positive for f32) ~ 1e-32). R3/R5/R6/R7 validated the predicate.
// ---------------------------------------------------------------------------
__device__ inline bool probe_is_bf16(const void* mfs) {
    const unsigned int* w = (const unsigned int*)mfs;
    bool ok = true;
#pragma unroll
    for (int k = 0; k < 15; ++k) {
        const unsigned int v = w[k];
        const float lo = __uint_as_float(v << 16);
        const float hi = __uint_as_float(v & 0xffff0000u);
        ok = ok && (lo >= 0.4f) && (lo <= 1.6f) && (hi >= 0.4f) && (hi <= 1.6f);
    }
    return ok;
}

// ---------------------------------------------------------------------------
// Main: block = (row group g: 256 rows) x (rule split s: 256 rules).
//   lane (0..63) covers rows {l, l+64, l+128, l+192} packed f16x4 (uint2);
//   one conflict-free ds_read_b64 serves 4 rows. wave (0..15) handles 16
//   rules; rule index wave-uniform -> packed/ow are LDS broadcast reads
//   (in-order with the gathers -> fine-grained lgkmcnt, no SMEM drains).
//   Cross-wave row reduction via LDS float atomics into acc[3][256].
// ---------------------------------------------------------------------------
__global__ __launch_bounds__(THREADS, 8)   // 8 waves/EU => VGPR<=64, 2 blocks/CU
void anfis_main(const void* __restrict__ x_,
                const void* __restrict__ mfc_,
                const void* __restrict__ mfs_,
                const void* __restrict__ oc_,
                const int*  __restrict__ input_rules,
                const int*  __restrict__ output_rules,
                float* __restrict__ partials) {
    __shared__ float        xs[N_IN][ROWS_PB];   // 6 KB, transposed: lane reads stride-1
    __shared__ float2       cinv[N_FUZZ];        // (center, 1/scale)
    __shared__ uint2        fuzz4[N_FUZZ][64];   // 15 KB, 4 rows/lane f16x4
    __shared__ unsigned int packed_lds[RULES_PB];// 1 KB (this block's split)
    __shared__ float2       ow_lds[RULES_PB];    // 2 KB
    __shared__ float        acc[3][ROWS_PB];     // 3 KB: l1/d0/d1 per row

    const int t     = threadIdx.x;
    const int g     = blockIdx.x >> 3;           // row group 0..63
    const int split = blockIdx.x & 7;            // rule split 0..7
    const int row0  = g * ROWS_PB;

    const bool is_bf16 = probe_is_bf16(mfs_);    // per-thread, L1-broadcast

    // ---- region 1: stage x (transposed) + MF params; zero acc ----
    if (is_bf16) {
        const unsigned short* xp = (const unsigned short*)x_ + row0 * N_IN;
        for (int i = t; i < ROWS_PB * N_IN; i += THREADS)
            xs[i % N_IN][i / N_IN] = __uint_as_float((unsigned int)xp[i] << 16);
    } else {
        const float* xp = (const float*)x_ + row0 * N_IN;
        for (int i = t; i < ROWS_PB * N_IN; i += THREADS)
            xs[i % N_IN][i / N_IN] = xp[i];
    }
    if (t < N_FUZZ) {
        float c, s;
        if (is_bf16) {
            c = __uint_as_float((unsigned int)((const unsigned short*)mfc_)[t] << 16);
            s = __uint_as_float((unsigned int)((const unsigned short*)mfs_)[t] << 16);
        } else {
            c = ((const float*)mfc_)[t];
            s = ((const float*)mfs_)[t];
        }
        cinv[t] = make_float2(c, 1.0f / s);
    }
    if (t < 3 * ROWS_PB) acc[0][t] = 0.0f;       // zero atomic accumulator
    __syncthreads();

    // ---- region 2: stage this split's rules (t<256; global-load latency
    // overlaps the fuzzify compute below) + fuzzify all 30x256 values ----
    if (t < RULES_PB) {
        const int r = split * RULES_PB + t;
        const int* rp = input_rules + r * N_IN;
        unsigned int p = 0;
#pragma unroll
        for (int i = 0; i < N_IN; ++i) p |= ((unsigned int)rp[i] & 31u) << (5 * i);
        packed_lds[t] = p;
        const int o0i = output_rules[2 * r + 0];
        const int o1i = output_rules[2 * r + 1];
        float o0, o1;
        if (is_bf16) {
            const unsigned short* oc = (const unsigned short*)oc_;
            o0 = __uint_as_float((unsigned int)oc[o0i] << 16);
            o1 = __uint_as_float((unsigned int)oc[o1i] << 16);
        } else {
            const float* oc = (const float*)oc_;
            o0 = oc[o0i]; o1 = oc[o1i];
        }
        ow_lds[t] = make_float2(o0, o1);
    }
    for (int e = t; e < N_FUZZ * 64; e += THREADS) {
        const int v    = e >> 6;    // MF value index 0..29
        const int lane = e & 63;
        const int i    = v / N_MF;  // input index
        const float2 ci = cinv[v];
        float f[4];
#pragma unroll
        for (int k = 0; k < 4; ++k) {
            const float z = (xs[i][lane + 64 * k] - ci.x) * ci.y;  // stride-1: free
            f[k] = __expf(-z * z);
        }
        f16x2 a = { (_Float16)f[0], (_Float16)f[1] };   // rows lane, lane+64
        f16x2 b = { (_Float16)f[2], (_Float16)f[3] };   // rows lane+128, +192
        uint2 u;
        u.x = __builtin_bit_cast(unsigned int, a);
        u.y = __builtin_bit_cast(unsigned int, b);
        fuzz4[v][lane] = u;
    }
    __syncthreads();

    // ---- region 3: rule loop — PURE LDS (no SMEM in the loop) ----
    const int lane = t & 63;
    const int wave = __builtin_amdgcn_readfirstlane(t >> 6);
    const uint2* fz = &fuzz4[0][0];

    float l1[4] = {0.f, 0.f, 0.f, 0.f};
    float d0[4] = {0.f, 0.f, 0.f, 0.f};
    float d1[4] = {0.f, 0.f, 0.f, 0.f};

    const int rbase = wave * RULES_PW;
#pragma unroll 4
    for (int j = 0; j < RULES_PW; ++j) {
        const int r2 = rbase + j;
        const unsigned int p = packed_lds[r2];   // LDS broadcast (in-order)
        const float2 o = ow_lds[r2];             // LDS broadcast (in-order)
        const uint2 g0 = fz[((p      ) & 31u) * 64 + lane];
        const uint2 g1 = fz[((p >> 5 ) & 31u) * 64 + lane];
        const uint2 g2 = fz[((p >> 10) & 31u) * 64 + lane];
        const uint2 g3 = fz[((p >> 15) & 31u) * 64 + lane];
        const uint2 g4 = fz[((p >> 20) & 31u) * 64 + lane];
        const uint2 g5 = fz[((p >> 25) & 31u) * 64 + lane];
        f16x2 wa = __builtin_elementwise_min(__builtin_bit_cast(f16x2, g0.x),
                                             __builtin_bit_cast(f16x2, g1.x));
        wa = __builtin_elementwise_min(wa, __builtin_bit_cast(f16x2, g2.x));
        wa = __builtin_elementwise_min(wa, __builtin_bit_cast(f16x2, g3.x));
        wa = __builtin_elementwise_min(wa, __builtin_bit_cast(f16x2, g4.x));
        wa = __builtin_elementwise_min(wa, __builtin_bit_cast(f16x2, g5.x));
        f16x2 wb = __builtin_elementwise_min(__builtin_bit_cast(f16x2, g0.y),
                                             __builtin_bit_cast(f16x2, g1.y));
        wb = __builtin_elementwise_min(wb, __builtin_bit_cast(f16x2, g2.y));
        wb = __builtin_elementwise_min(wb, __builtin_bit_cast(f16x2, g3.y));
        wb = __builtin_elementwise_min(wb, __builtin_bit_cast(f16x2, g4.y));
        wb = __builtin_elementwise_min(wb, __builtin_bit_cast(f16x2, g5.y));
        const float w0 = (float)wa.x, w1 = (float)wa.y;
        const float w2 = (float)wb.x, w3 = (float)wb.y;
        l1[0] += w0; d0[0] += w0 * o.x; d1[0] += w0 * o.y;
        l1[1] += w1; d0[1] += w1 * o.x; d1[1] += w1 * o.y;
        l1[2] += w2; d0[2] += w2 * o.x; d1[2] += w2 * o.y;
        l1[3] += w3; d0[3] += w3 * o.x; d1[3] += w3 * o.y;
    }

    // ---- cross-wave reduction: ds_add_f32 into acc (bank=row%32, 2-way free) ----
#pragma unroll
    for (int k = 0; k < 4; ++k) {
        const int row = lane + 64 * k;
        atomicAdd(&acc[0][row], l1[k]);
        atomicAdd(&acc[1][row], d0[k]);
        atomicAdd(&acc[2][row], d1[k]);
    }
    __syncthreads();

    // ---- write this split's partials ----
    if (t < ROWS_PB) {
        const int row = row0 + t;
        partials[(split * 3 + 0) * BATCH + row] = acc[0][t];
        partials[(split * 3 + 1) * BATCH + row] = acc[1][t];
        partials[(split * 3 + 2) * BATCH + row] = acc[2][t];
    }
}

// ---------------------------------------------------------------------------
// Finalize: sum the 8 rule-split partials per row, normalize, tanh, store.
// (Separate dispatch: R6 proved an in-kernel device-fence finalize costs ~90us.)
// ---------------------------------------------------------------------------
__global__ void anfis_finalize(const float* __restrict__ partials,
                               const void* __restrict__ mfs_,
                               void* __restrict__ out_) {
    const bool is_bf16 = probe_is_bf16(mfs_);
    const int row = blockIdx.x * blockDim.x + threadIdx.x;
    if (row >= BATCH) return;
    float l1 = 0.f, d0 = 0.f, d1 = 0.f;
#pragma unroll
    for (int s = 0; s < SPLITS; ++s) {
        l1 += partials[(s * 3 + 0) * BATCH + row];
        d0 += partials[(s * 3 + 1) * BATCH + row];
        d1 += partials[(s * 3 + 2) * BATCH + row];
    }
    const float inv = 1.0f / fmaxf(l1, 1e-12f);
    const float y0 = tanhf(d0 * inv) * 4.00f + 0.00f;
    const float y1 = tanhf(d1 * inv) * 0.75f + 0.75f;
    if (is_bf16) {
        __hip_bfloat162 o;
        o.x = __float2bfloat16(y0);
        o.y = __float2bfloat16(y1);
        ((__hip_bfloat162*)out_)[row] = o;
    } else {
        ((float2*)out_)[row] = make_float2(y0, y1);
    }
}

extern "C" void kernel_launch(void* const* d_in, const int* in_sizes, int n_in,
                              void* d_out, int out_size, void* d_ws, size_t ws_size,
                              hipStream_t stream) {
    (void)in_sizes; (void)n_in; (void)out_size; (void)ws_size;
    float* parts = (float*)((char*)d_ws + WS_PART_OFF);

    anfis_main<<<ROWGROUPS * SPLITS, THREADS, 0, stream>>>(
        d_in[0], d_in[1], d_in[2], d_in[3],
        (const int*)d_in[4], (const int*)d_in[5], parts);

    anfis_finalize<<<BATCH / 256, 256, 0, stream>>>(parts, d_in[2], d_out);
}

// Round 9
// 81.910 us; speedup vs baseline: 2.0358x; 1.3217x over previous
//
#include <hip/hip_runtime.h>
#include <hip/hip_bf16.h>

// Problem constants (JointAnfisNet)
#define BATCH      16384
#define N_IN       6
#define N_MF       5
#define N_FUZZ     30      // N_IN * N_MF
#define N_RULES    2048

// R9: revert to the best-measured decomposition (R5: 4 splits, 32 rules/wave,
// wave-partial LDS arrays, 1 block/CU) and attack the R8 finding that
// VGPR=20 strangled gather ILP: launch_bounds (1024,4) -> VGPR cap 128, and
// the rule loop batches 2 rules' worth of gathers (12 independent b64) before
// consuming any. Rule prep fused into the block (R7->R8 proved LDS-staged
// rules are perf-neutral vs scalar loads) to delete the prep dispatch.
#define ROWS_PB    256
#define SPLITS     4
#define RULES_PB   (N_RULES / SPLITS)     // 512
#define THREADS    1024
#define WAVES      16
#define RULES_PW   (RULES_PB / WAVES)     // 32
#define ROWGROUPS  (BATCH / ROWS_PB)      // 64

// d_ws layout: partials f32[SPLITS*3*BATCH] = 768 KB
#define WS_PART_OFF  0

// Packed f16 pair; __builtin_elementwise_min lowers to v_pk_min_f16.
typedef _Float16 f16x2 __attribute__((ext_vector_type(2)));

// ---------------------------------------------------------------------------
// Deterministic dtype probe (branchless, 15 independent loads, one wait).
// mf_scales is genuinely in [0.5,1.5]; read as 30 bf16 halves, all-in-
// [0.4,1.6] => bf16 data (P(false positive for f32) ~ 1e-32). R3..R8 passed.
// ---------------------------------------------------------------------------
__device__ inline bool probe_is_bf16(const void* mfs) {
    const unsigned int* w = (const unsigned int*)mfs;
    bool ok = true;
#pragma unroll
    for (int k = 0; k < 15; ++k) {
        const unsigned int v = w[k];
        const float lo = __uint_as_float(v << 16);
        const float hi = __uint_as_float(v & 0xffff0000u);
        ok = ok && (lo >= 0.4f) && (lo <= 1.6f) && (hi >= 0.4f) && (hi <= 1.6f);
    }
    return ok;
}

// Min-reduce 6 packed f16 pairs as a depth-3 tree (shorter dep chain than a
// serial 5-step chain).
__device__ inline f16x2 min6(f16x2 a0, f16x2 a1, f16x2 a2,
                             f16x2 a3, f16x2 a4, f16x2 a5) {
    const f16x2 m01 = __builtin_elementwise_min(a0, a1);
    const f16x2 m23 = __builtin_elementwise_min(a2, a3);
    const f16x2 m45 = __builtin_elementwise_min(a4, a5);
    return __builtin_elementwise_min(__builtin_elementwise_min(m01, m23), m45);
}

// ---------------------------------------------------------------------------
// Main: block = (row group g: 256 rows) x (rule split s: 512 rules).
//   lane (0..63) covers rows {l, l+64, l+128, l+192} packed f16x4 (uint2);
//   one conflict-free ds_read_b64 serves 4 rows. wave (0..15) handles 32
//   rules. Cross-wave reduction via [16][256] wave-partial arrays (48 KB,
//   R5-style; LDS atomics regressed in R7/R8). ~77 KB LDS -> 1 block/CU,
//   16 waves/CU — measured better than R7/R8's 32 waves/CU.
// ---------------------------------------------------------------------------
__global__ __launch_bounds__(THREADS, 4)   // VGPR cap 128: room for gather ILP
void anfis_main(const void* __restrict__ x_,
                const void* __restrict__ mfc_,
                const void* __restrict__ mfs_,
                const void* __restrict__ oc_,
                const int*  __restrict__ input_rules,
                const int*  __restrict__ output_rules,
                float* __restrict__ partials) {
    __shared__ float        xs[N_IN][ROWS_PB];    // 6 KB transposed
    __shared__ float2       cinv[N_FUZZ];         // (center, 1/scale)
    __shared__ uint2        fuzz4[N_FUZZ][64];    // 15 KB, 4 rows/lane f16x4
    __shared__ unsigned int packed_lds[RULES_PB]; // 2 KB (this block's split)
    __shared__ float2       ow_lds[RULES_PB];     // 4 KB
    __shared__ float        pl1[WAVES][ROWS_PB];  // 16 KB
    __shared__ float        pd0[WAVES][ROWS_PB];  // 16 KB
    __shared__ float        pd1[WAVES][ROWS_PB];  // 16 KB

    const int t     = threadIdx.x;
    const int g     = blockIdx.x >> 2;            // row group 0..63
    const int split = blockIdx.x & 3;             // rule split 0..3
    const int row0  = g * ROWS_PB;

    const bool is_bf16 = probe_is_bf16(mfs_);

    // ---- region 1: stage x (transposed) + MF params ----
    if (is_bf16) {
        const unsigned short* xp = (const unsigned short*)x_ + row0 * N_IN;
        for (int i = t; i < ROWS_PB * N_IN; i += THREADS)
            xs[i % N_IN][i / N_IN] = __uint_as_float((unsigned int)xp[i] << 16);
    } else {
        const float* xp = (const float*)x_ + row0 * N_IN;
        for (int i = t; i < ROWS_PB * N_IN; i += THREADS)
            xs[i % N_IN][i / N_IN] = xp[i];
    }
    if (t < N_FUZZ) {
        float c, s;
        if (is_bf16) {
            c = __uint_as_float((unsigned int)((const unsigned short*)mfc_)[t] << 16);
            s = __uint_as_float((unsigned int)((const unsigned short*)mfs_)[t] << 16);
        } else {
            c = ((const float*)mfc_)[t];
            s = ((const float*)mfs_)[t];
        }
        cinv[t] = make_float2(c, 1.0f / s);
    }
    // ---- region 1b: stage this split's 512 rules (t<512); the global-load
    // latency overlaps the fuzzify work after the barrier ----
    if (t < RULES_PB) {
        const int r = split * RULES_PB + t;
        const int* rp = input_rules + r * N_IN;
        unsigned int p = 0;
#pragma unroll
        for (int i = 0; i < N_IN; ++i) p |= ((unsigned int)rp[i] & 31u) << (5 * i);
        packed_lds[t] = p;
        const int o0i = output_rules[2 * r + 0];
        const int o1i = output_rules[2 * r + 1];
        float o0, o1;
        if (is_bf16) {
            const unsigned short* oc = (const unsigned short*)oc_;
            o0 = __uint_as_float((unsigned int)oc[o0i] << 16);
            o1 = __uint_as_float((unsigned int)oc[o1i] << 16);
        } else {
            const float* oc = (const float*)oc_;
            o0 = oc[o0i]; o1 = oc[o1i];
        }
        ow_lds[t] = make_float2(o0, o1);
    }
    __syncthreads();

    // ---- region 2: fuzzify. 30 x 64 uint2, each = 4 rows' exp(-z^2) f16 ----
    for (int e = t; e < N_FUZZ * 64; e += THREADS) {
        const int v    = e >> 6;    // MF value index 0..29
        const int lane = e & 63;
        const int i    = v / N_MF;  // input index
        const float2 ci = cinv[v];
        float f[4];
#pragma unroll
        for (int k = 0; k < 4; ++k) {
            const float z = (xs[i][lane + 64 * k] - ci.x) * ci.y;
            f[k] = __expf(-z * z);
        }
        f16x2 a = { (_Float16)f[0], (_Float16)f[1] };
        f16x2 b = { (_Float16)f[2], (_Float16)f[3] };
        uint2 u;
        u.x = __builtin_bit_cast(unsigned int, a);
        u.y = __builtin_bit_cast(unsigned int, b);
        fuzz4[v][lane] = u;
    }
    __syncthreads();

    // ---- region 3: rule loop, 2 rules interleaved per iteration. All 12
    // gathers issue before any consumption -> deep ds_read pipelining. ----
    const int lane = t & 63;
    const int wave = __builtin_amdgcn_readfirstlane(t >> 6);
    const uint2* fz = &fuzz4[0][0];

    float l1[4] = {0.f, 0.f, 0.f, 0.f};
    float d0[4] = {0.f, 0.f, 0.f, 0.f};
    float d1[4] = {0.f, 0.f, 0.f, 0.f};

    const int rbase = wave * RULES_PW;
#pragma unroll 4
    for (int j = 0; j < RULES_PW; j += 2) {
        const int rA = rbase + j;
        const int rB = rA + 1;
        const unsigned int pA = packed_lds[rA];
        const unsigned int pB = packed_lds[rB];
        const float2 oA = ow_lds[rA];
        const float2 oB = ow_lds[rB];
        uint2 gA[6], gB[6];
#pragma unroll
        for (int q = 0; q < 6; ++q)
            gA[q] = fz[((pA >> (5 * q)) & 31u) * 64 + lane];
#pragma unroll
        for (int q = 0; q < 6; ++q)
            gB[q] = fz[((pB >> (5 * q)) & 31u) * 64 + lane];

        const f16x2 waA = min6(__builtin_bit_cast(f16x2, gA[0].x), __builtin_bit_cast(f16x2, gA[1].x),
                               __builtin_bit_cast(f16x2, gA[2].x), __builtin_bit_cast(f16x2, gA[3].x),
                               __builtin_bit_cast(f16x2, gA[4].x), __builtin_bit_cast(f16x2, gA[5].x));
        const f16x2 wbA = min6(__builtin_bit_cast(f16x2, gA[0].y), __builtin_bit_cast(f16x2, gA[1].y),
                               __builtin_bit_cast(f16x2, gA[2].y), __builtin_bit_cast(f16x2, gA[3].y),
                               __builtin_bit_cast(f16x2, gA[4].y), __builtin_bit_cast(f16x2, gA[5].y));
        const f16x2 waB = min6(__builtin_bit_cast(f16x2, gB[0].x), __builtin_bit_cast(f16x2, gB[1].x),
                               __builtin_bit_cast(f16x2, gB[2].x), __builtin_bit_cast(f16x2, gB[3].x),
                               __builtin_bit_cast(f16x2, gB[4].x), __builtin_bit_cast(f16x2, gB[5].x));
        const f16x2 wbB = min6(__builtin_bit_cast(f16x2, gB[0].y), __builtin_bit_cast(f16x2, gB[1].y),
                               __builtin_bit_cast(f16x2, gB[2].y), __builtin_bit_cast(f16x2, gB[3].y),
                               __builtin_bit_cast(f16x2, gB[4].y), __builtin_bit_cast(f16x2, gB[5].y));

        const float wA0 = (float)waA.x, wA1 = (float)waA.y;
        const float wA2 = (float)wbA.x, wA3 = (float)wbA.y;
        l1[0] += wA0; d0[0] += wA0 * oA.x; d1[0] += wA0 * oA.y;
        l1[1] += wA1; d0[1] += wA1 * oA.x; d1[1] += wA1 * oA.y;
        l1[2] += wA2; d0[2] += wA2 * oA.x; d1[2] += wA2 * oA.y;
        l1[3] += wA3; d0[3] += wA3 * oA.x; d1[3] += wA3 * oA.y;
        const float wB0 = (float)waB.x, wB1 = (float)waB.y;
        const float wB2 = (float)wbB.x, wB3 = (float)wbB.y;
        l1[0] += wB0; d0[0] += wB0 * oB.x; d1[0] += wB0 * oB.y;
        l1[1] += wB1; d0[1] += wB1 * oB.x; d1[1] += wB1 * oB.y;
        l1[2] += wB2; d0[2] += wB2 * oB.x; d1[2] += wB2 * oB.y;
        l1[3] += wB3; d0[3] += wB3 * oB.x; d1[3] += wB3 * oB.y;
    }
#pragma unroll
    for (int k = 0; k < 4; ++k) {
        pl1[wave][lane + 64 * k] = l1[k];
        pd0[wave][lane + 64 * k] = d0[k];
        pd1[wave][lane + 64 * k] = d1[k];
    }
    __syncthreads();

    // ---- region 4: reduce 16 wave-partials per row; write split partials ----
    if (t < ROWS_PB) {
        float a = 0.f, b = 0.f, c = 0.f;
#pragma unroll
        for (int wv = 0; wv < WAVES; ++wv) {
            a += pl1[wv][t];
            b += pd0[wv][t];
            c += pd1[wv][t];
        }
        const int row = row0 + t;
        partials[(split * 3 + 0) * BATCH + row] = a;
        partials[(split * 3 + 1) * BATCH + row] = b;
        partials[(split * 3 + 2) * BATCH + row] = c;
    }
}

// ---------------------------------------------------------------------------
// Finalize: sum the 4 rule-split partials per row, normalize, tanh, store.
// (Separate dispatch: R6 proved in-kernel device-fence finalize costs ~90us.)
// ---------------------------------------------------------------------------
__global__ void anfis_finalize(const float* __restrict__ partials,
                               const void* __restrict__ mfs_,
                               void* __restrict__ out_) {
    const bool is_bf16 = probe_is_bf16(mfs_);
    const int row = blockIdx.x * blockDim.x + threadIdx.x;
    if (row >= BATCH) return;
    float l1 = 0.f, d0 = 0.f, d1 = 0.f;
#pragma unroll
    for (int s = 0; s < SPLITS; ++s) {
        l1 += partials[(s * 3 + 0) * BATCH + row];
        d0 += partials[(s * 3 + 1) * BATCH + row];
        d1 += partials[(s * 3 + 2) * BATCH + row];
    }
    const float inv = 1.0f / fmaxf(l1, 1e-12f);
    const float y0 = tanhf(d0 * inv) * 4.00f + 0.00f;
    const float y1 = tanhf(d1 * inv) * 0.75f + 0.75f;
    if (is_bf16) {
        __hip_bfloat162 o;
        o.x = __float2bfloat16(y0);
        o.y = __float2bfloat16(y1);
        ((__hip_bfloat162*)out_)[row] = o;
    } else {
        ((float2*)out_)[row] = make_float2(y0, y1);
    }
}

extern "C" void kernel_launch(void* const* d_in, const int* in_sizes, int n_in,
                              void* d_out, int out_size, void* d_ws, size_t ws_size,
                              hipStream_t stream) {
    (void)in_sizes; (void)n_in; (void)out_size; (void)ws_size;
    float* parts = (float*)((char*)d_ws + WS_PART_OFF);

    anfis_main<<<ROWGROUPS * SPLITS, THREADS, 0, stream>>>(
        d_in[0], d_in[1], d_in[2], d_in[3],
        (const int*)d_in[4], (const int*)d_in[5], parts);

    anfis_finalize<<<BATCH / 256, 256, 0, stream>>>(parts, d_in[2], d_out);
}